// Round 14
// baseline (219.589 us; speedup 1.0000x reference)
//
#include <hip/hip_runtime.h>
#include <hip/hip_fp16.h>

// B=2, H=16, N=2048, D=128 ; fp32 in, fp32 out
#define BH   32
#define SEQ  2048
#define DIM  128
#define CK   32              // keys per chunk
#define NCH  (SEQ / CK)      // 64
#define CSZ  (CK * DIM)      // 4096 halves per chunk

typedef _Float16 half8   __attribute__((ext_vector_type(8)));
typedef __fp16   fp16x2  __attribute__((ext_vector_type(2)));
typedef _Float16 half2v  __attribute__((ext_vector_type(2)));
typedef float    floatx4 __attribute__((ext_vector_type(4)));
typedef float    floatx16 __attribute__((ext_vector_type(16)));

__device__ inline half2v pk2(float a, float b) {
    fp16x2 t = __builtin_amdgcn_cvt_pkrtz(a, b);
    return *(half2v*)&t;
}
__device__ inline unsigned pk2u(float a, float b) {
    fp16x2 t = __builtin_amdgcn_cvt_pkrtz(a, b);
    return *(unsigned*)&t;
}
__device__ inline half8 pk8(float4 a, float4 b) {
    half2v l0 = pk2(a.x, a.y), l1 = pk2(a.z, a.w);
    half2v l2 = pk2(b.x, b.y), l3 = pk2(b.z, b.w);
    half8 h;
    h[0] = l0[0]; h[1] = l0[1]; h[2] = l1[0]; h[3] = l1[1];
    h[4] = l2[0]; h[5] = l2[1]; h[6] = l3[0]; h[7] = l3[1];
    return h;
}

// async global->LDS, 16B per lane; LDS dest = wave-uniform base + lane*16
__device__ inline void ld16(const void* g, void* l) {
    __builtin_amdgcn_global_load_lds(
        (__attribute__((address_space(1))) void*)(uintptr_t)g,
        (__attribute__((address_space(3))) void*)(uintptr_t)l, 16, 0, 0);
}

// drain own DMAs (issued a full chunk ago) AND own LDS reads (2-buffer carry),
// then workgroup barrier. R9/R13: the lgkm drain is ~free here.
#define SYNC_VML do {                                              \
    asm volatile("s_waitcnt vmcnt(0) lgkmcnt(0)" ::: "memory");    \
    __builtin_amdgcn_s_barrier();                                  \
    asm volatile("" ::: "memory");                                 \
} while (0)

// ---------- fused prepass: K cvt (+scale) and V transpose, chunk-tiled ----------
// K out: kh[bh][n][d] fp16 (row-major)
// V out: vt[bh][kc][d=128][key=32] fp16 (8 KiB contiguous per chunk)
__global__ void prep_kernel(const float* __restrict__ k, const float* __restrict__ v,
                            _Float16* __restrict__ kh, _Float16* __restrict__ vt) {
    const float SC = 0.08838834764831845f * 1.4426950408889634f; // 1/sqrt(128)*log2(e)
    __shared__ __align__(16) _Float16 t[32][136];
    const int bh = blockIdx.x >> 6;
    const int kc = blockIdx.x & 63;
    const int tid = threadIdx.x;
    const size_t base = ((size_t)bh * SEQ + kc * CK) * DIM;   // floats (4096 per chunk)

    const float4* kf4 = (const float4*)(k + base);
    const float4* vf4 = (const float4*)(v + base);
    half8* kh8 = (half8*)(kh + base);

    #pragma unroll
    for (int i = 0; i < 2; i++) {
        int f8 = i * 256 + tid;                 // 0..511 granules of 8 elems
        float4 a = kf4[2 * f8], b = kf4[2 * f8 + 1];
        a.x *= SC; a.y *= SC; a.z *= SC; a.w *= SC;
        b.x *= SC; b.y *= SC; b.z *= SC; b.w *= SC;
        kh8[f8] = pk8(a, b);
        int row = f8 >> 4, c8 = f8 & 15;
        *((half8*)&t[row][c8 * 8]) = pk8(vf4[2 * f8], vf4[2 * f8 + 1]);
    }
    __syncthreads();
    _Float16* vout = vt + ((size_t)bh * NCH + kc) * (DIM * CK);
    #pragma unroll
    for (int i = 0; i < 2; i++) {
        int g = i * 256 + tid;                  // 0..511 = 128 d x 4 key-granules
        int d = g >> 2, kg = g & 3;
        half8 h;
        #pragma unroll
        for (int j = 0; j < 8; j++) h[j] = t[kg * 8 + j][d];
        *((half8*)(vout + d * CK + kg * 8)) = h;
    }
}

// ---------- main: flash attention, 32x32x16 MFMA, swapped-QK in-register P ----------
// 256-thread blocks, 4 waves x 32 Q-rows (one 32-row set per wave). Per chunk:
// 18 MFMAs of 32x32x16 (8 QK + 8 PV + 2 Osum) vs 34 of 16x16x32 before:
// +21% FLOP/cyc on the matrix pipe, half the MFMA issue slots.
__global__ __launch_bounds__(256, 2) void attn_kernel(
        const float* __restrict__ q, const _Float16* __restrict__ kh,
        const _Float16* __restrict__ vt, float* __restrict__ out) {
    // K LDS: [key][d] 32x128, granule position p = g ^ (key&7)  (conflict-free)
    // V LDS: [d][key] 128x32, granule position p = g ^ (d&3)    (2-way = free)
    __shared__ __align__(16) _Float16 Kbuf[2][CSZ];    // 2 x 8 KiB
    __shared__ __align__(16) _Float16 Vbuf[2][CSZ];    // 2 x 8 KiB

    // bijective XCD swizzle: 4 bh per XCD so each XCD L2 streams 4 heads' K/V
    const int lid = blockIdx.x + (blockIdx.y << 4);   // 0..511, x fastest
    const int xcd = lid & 7;
    const int idx = lid >> 3;                         // 0..63
    const int bh  = (xcd << 2) + (idx >> 4);
    const int qt  = idx & 15;

    const int tid  = threadIdx.x;
    const int w    = tid >> 6;            // wave: rows qt*128 + w*32 + {0..31}
    const int lane = tid & 63;
    const int l31  = lane & 31;
    const int hi   = lane >> 5;           // half-wave 0/1

    // Q fragments (B-operand): lane holds q-col = l31, k-elems d = ki*16+hi*8+j
    half8 qf[8];
    {
        const float* qb = q + ((size_t)bh * SEQ + qt * 128 + w * 32 + l31) * DIM + hi * 8;
        #pragma unroll
        for (int ki = 0; ki < 8; ki++) {
            float4 a = *((const float4*)(qb + ki * 16));
            float4 b = *((const float4*)(qb + ki * 16 + 4));
            qf[ki] = pk8(a, b);
        }
    }

    half8 ones;
    #pragma unroll
    for (int j = 0; j < 8; j++) ones[j] = (_Float16)1.0f;

    floatx16 zf16;
    #pragma unroll
    for (int i = 0; i < 16; i++) zf16[i] = 0.f;

    floatx16 O[4];      // d-tiles of 32: C col = d32 = l31, row q(r,hi)
    #pragma unroll
    for (int dtv = 0; dtv < 4; dtv++) O[dtv] = zf16;
    floatx16 Osum = zf16;

    const _Float16* kb = kh + (size_t)bh * SEQ * DIM;
    const _Float16* vb = vt + (size_t)bh * SEQ * DIM;

    // DMA slots (16B granules), LDS dest linear s*16.
    // K slot s: key=s>>4, pos p=s&15 -> global granule g = p ^ (key&7)
    // V slot s: d=s>>2,  pos p=s&3  -> global granule g = p ^ (d&3)
    const int sk0 = tid, sk1 = tid + 256;
    const _Float16* kgp0 = kb + (sk0 >> 4) * DIM + (((sk0 & 15) ^ ((sk0 >> 4) & 7)) * 8);
    const _Float16* kgp1 = kb + (sk1 >> 4) * DIM + (((sk1 & 15) ^ ((sk1 >> 4) & 7)) * 8);
    const _Float16* vgp0 = vb + (sk0 >> 2) * CK + (((sk0 & 3) ^ ((sk0 >> 2) & 3)) * 8);
    const _Float16* vgp1 = vb + (sk1 >> 2) * CK + (((sk1 & 3) ^ ((sk1 >> 2) & 3)) * 8);

    auto dma = [&](int kc, int b_) {
        size_t off = (size_t)kc * CSZ;
        ld16(kgp0 + off, &Kbuf[b_][w * 512]);
        ld16(kgp1 + off, &Kbuf[b_][2048 + w * 512]);
        ld16(vgp0 + off, &Vbuf[b_][w * 512]);
        ld16(vgp1 + off, &Vbuf[b_][2048 + w * 512]);
    };

    // pipeline-carried state: P A-frags (2 k-slices) and V B-frags of chunk kc-1
    half8 pf[2];
    half8 vfr[4][2];
    #pragma unroll
    for (int i = 0; i < 2; i++)
        #pragma unroll
        for (int j = 0; j < 8; j++) pf[i][j] = (_Float16)0.0f;
    #pragma unroll
    for (int dtv = 0; dtv < 4; dtv++)
        #pragma unroll
        for (int ks = 0; ks < 2; ks++)
            #pragma unroll
            for (int j = 0; j < 8; j++) vfr[dtv][ks][j] = (_Float16)0.0f;

    // chunk body: QK(kc) -> PV(kc-1) -> V(kc)->vfr -> exp2/pack/half-swap -> pf
    auto body = [&](int b_) {
        const _Float16* Kc = Kbuf[b_];
        const _Float16* Vc = Vbuf[b_];

        // ---- S^T(kc) = K*Q : A=K (row=key=l31, k=d), B=Q (col=q=l31) ----
        // C: col q = l31, reg r -> key = (r&3) + 8*(r>>2) + 4*hi
        floatx16 S = zf16;
        __builtin_amdgcn_s_setprio(1);
        #pragma unroll
        for (int ki = 0; ki < 8; ki++) {
            half8 kf = *((const half8*)&Kc[l31 * DIM + (((ki * 2 + hi) ^ (l31 & 7)) * 8)]);
            S = __builtin_amdgcn_mfma_f32_32x32x16_f16(kf, qf[ki], S, 0, 0, 0);
        }
        __builtin_amdgcn_s_setprio(0);

        // ---- PV(kc-1): A=P(row=q), B=V(col=d32) -- register-only MFMAs ----
        __builtin_amdgcn_s_setprio(1);
        Osum = __builtin_amdgcn_mfma_f32_32x32x16_f16(pf[0], ones, Osum, 0, 0, 0);
        Osum = __builtin_amdgcn_mfma_f32_32x32x16_f16(pf[1], ones, Osum, 0, 0, 0);
        #pragma unroll
        for (int dtv = 0; dtv < 4; dtv++) {
            O[dtv] = __builtin_amdgcn_mfma_f32_32x32x16_f16(pf[0], vfr[dtv][0], O[dtv], 0, 0, 0);
            O[dtv] = __builtin_amdgcn_mfma_f32_32x32x16_f16(pf[1], vfr[dtv][1], O[dtv], 0, 0, 0);
        }
        __builtin_amdgcn_s_setprio(0);

        // ---- V(kc) B-frags: lane col d32=l31, k = ks*16 + hi*8 + j ----
        #pragma unroll
        for (int dtv = 0; dtv < 4; dtv++)
            #pragma unroll
            for (int ks = 0; ks < 2; ks++)
                vfr[dtv][ks] = *((const half8*)&Vc[(dtv * 32 + l31) * CK +
                                                   (((ks * 2 + hi) ^ (lane & 3)) * 8)]);

        // ---- P(kc): exp2, pack, half-wave swap into A-frag layout ----
        // reg r holds key (r&3)+8*(r>>2)+4*hi; A-frag needs k = ks*16+hi*8+j.
        unsigned wv[8], xv[8];
        #pragma unroll
        for (int i = 0; i < 8; i++) {
            float e0 = __builtin_amdgcn_exp2f(S[2 * i]);
            float e1 = __builtin_amdgcn_exp2f(S[2 * i + 1]);
            wv[i] = pk2u(e0, e1);
        }
        #pragma unroll
        for (int i = 0; i < 8; i++) xv[i] = __shfl_xor((int)wv[i], 32);
        union { unsigned u[4]; half8 h; } c0, c1;
        c0.u[0] = hi ? xv[2] : wv[0];
        c0.u[1] = hi ? xv[3] : wv[1];
        c0.u[2] = hi ? wv[2] : xv[0];
        c0.u[3] = hi ? wv[3] : xv[1];
        c1.u[0] = hi ? xv[6] : wv[4];
        c1.u[1] = hi ? xv[7] : wv[5];
        c1.u[2] = hi ? wv[6] : xv[4];
        c1.u[3] = hi ? wv[7] : xv[5];
        pf[0] = c0.h;
        pf[1] = c1.h;
    };

    // prologue: 1 chunk in flight; PV(-1) is 0x0
    dma(0, 0);

    #pragma unroll 2
    for (int kc = 0; kc < NCH; kc++) {
        SYNC_VML;
        if (kc + 1 < NCH) dma(kc + 1, (kc + 1) & 1);
        body(kc & 1);
    }

    // ---- final PV(NCH-1) ----
    __builtin_amdgcn_s_setprio(1);
    Osum = __builtin_amdgcn_mfma_f32_32x32x16_f16(pf[0], ones, Osum, 0, 0, 0);
    Osum = __builtin_amdgcn_mfma_f32_32x32x16_f16(pf[1], ones, Osum, 0, 0, 0);
    #pragma unroll
    for (int dtv = 0; dtv < 4; dtv++) {
        O[dtv] = __builtin_amdgcn_mfma_f32_32x32x16_f16(pf[0], vfr[dtv][0], O[dtv], 0, 0, 0);
        O[dtv] = __builtin_amdgcn_mfma_f32_32x32x16_f16(pf[1], vfr[dtv][1], O[dtv], 0, 0, 0);
    }
    __builtin_amdgcn_s_setprio(0);

    // epilogue: normalize, store fp32.
    // O[dtv] reg r: row q = (r&3)+8*(r>>2)+4*hi, col d = dtv*32 + l31.
    // Osum reg r: same row mapping (cols replicated).
    {
        float* ob = out + ((size_t)bh * SEQ + qt * 128 + w * 32) * DIM;
        #pragma unroll
        for (int r = 0; r < 16; r++) {
            int qrow = (r & 3) + 8 * (r >> 2) + 4 * hi;
            float rinv = 1.0f / Osum[r];
            #pragma unroll
            for (int dtv = 0; dtv < 4; dtv++) {
                ob[(size_t)qrow * DIM + dtv * 32 + l31] = O[dtv][r] * rinv;
            }
        }
    }
}

extern "C" void kernel_launch(void* const* d_in, const int* in_sizes, int n_in,
                              void* d_out, int out_size, void* d_ws, size_t ws_size,
                              hipStream_t stream) {
    const float* q = (const float*)d_in[0];
    const float* k = (const float*)d_in[1];
    const float* v = (const float*)d_in[2];
    float* out = (float*)d_out;

    const size_t elems = (size_t)BH * SEQ * DIM;   // 8,388,608
    _Float16* kh = (_Float16*)d_ws;                // 16 MiB
    _Float16* vtp = kh + elems;                    // 16 MiB (chunk-tiled)

    prep_kernel<<<BH * NCH, 256, 0, stream>>>(k, v, kh, vtp);
    attn_kernel<<<dim3(SEQ / 128, BH), 256, 0, stream>>>(q, kh, vtp, out);
}